// Round 3
// baseline (446.940 us; speedup 1.0000x reference)
//
#include <hip/hip_runtime.h>
#include <math.h>

typedef short bf16x8 __attribute__((ext_vector_type(8)));
typedef float f32x4 __attribute__((ext_vector_type(4)));

#define MFMA_BF16(A,B,C) __builtin_amdgcn_mfma_f32_16x16x32_bf16(A,B,C,0,0,0)

__device__ __forceinline__ unsigned short f2b(float x) {
    union { float f; unsigned int u; } v; v.f = x;
    unsigned int r = v.u + 0x7FFFu + ((v.u >> 16) & 1u);
    return (unsigned short)(r >> 16);
}

// ---------------------------------------------------------------------------
// fp32 -> bf16 convert (flat)
// ---------------------------------------------------------------------------
__global__ __launch_bounds__(256) void conv_bf16(const float* __restrict__ s,
                                                 unsigned short* __restrict__ d, int n)
{
    int i = blockIdx.x * blockDim.x + threadIdx.x;
    int stride = gridDim.x * blockDim.x;
    for (int idx = i * 4; idx < n; idx += stride * 4) {
        float4 v = *(const float4*)(s + idx);
        ushort4 o;
        o.x = f2b(v.x); o.y = f2b(v.y); o.z = f2b(v.z); o.w = f2b(v.w);
        *(ushort4*)(d + idx) = o;
    }
}

// ---------------------------------------------------------------------------
// fp32 [R][C] -> bf16 transposed [C][R] (dst pitch = R). R,C multiples of 32.
// ---------------------------------------------------------------------------
__global__ __launch_bounds__(256) void transp_conv(const float* __restrict__ src, int R, int C,
                                                   unsigned short* __restrict__ dst, int pitch)
{
    __shared__ float t[32][33];
    const int tx = threadIdx.x, ty = threadIdx.y;   // (32,8)
    const int c = blockIdx.x * 32 + tx;
    const int r0 = blockIdx.y * 32;
#pragma unroll
    for (int i = 0; i < 4; ++i)
        t[ty + i * 8][tx] = src[(size_t)(r0 + ty + i * 8) * C + c];
    __syncthreads();
    const int cc = blockIdx.x * 32 + ty;
#pragma unroll
    for (int i = 0; i < 4; ++i)
        dst[(size_t)(cc + i * 8) * pitch + r0 + tx] = f2b(t[tx][ty + i * 8]);
}

// ---------------------------------------------------------------------------
// bf16 MFMA GEMM, B^T input: C[M][N] = A[M][K] @ Bt[N][K]^T
// 128x128 tile, BK=32, 256 threads (4 waves, 2x2), 16x16x32 MFMA.
// MODE 0: plain fp32 store to Cf[M][N]
// MODE 1: fused QKV epilogue (block-uniform routing by n0):
//         n<1024  -> qh[m][n]          = bf16(tanh)
//         n<1280  -> kh[m][n-1024]     = bf16(tanh)
//         else    -> vtt[(b*4+g)*64+v][s] = bf16(sigmoid)   (V transposed)
// ---------------------------------------------------------------------------
template <int MODE>
__global__ __launch_bounds__(256) void gemm_bt_mfma(
    const unsigned short* __restrict__ A,
    const unsigned short* __restrict__ Bt,
    int M, int N, int K,
    float* __restrict__ Cf,
    unsigned short* __restrict__ qh,
    unsigned short* __restrict__ kh,
    unsigned short* __restrict__ vtt)
{
    __shared__ __align__(16) unsigned short As[128][40];   // pitch 40 bf16 = 80B (16B mult)
    __shared__ __align__(16) unsigned short Bs[128][40];

    const int tid = threadIdx.x;
    const int w = tid >> 6, lane = tid & 63, l15 = lane & 15, quad = lane >> 4;
    const int wm = w & 1, wn = w >> 1;
    const int m0 = blockIdx.y * 128, n0 = blockIdx.x * 128;

    f32x4 acc[4][4];
    const f32x4 zero4 = {0.f, 0.f, 0.f, 0.f};
#pragma unroll
    for (int i = 0; i < 4; ++i)
#pragma unroll
        for (int j = 0; j < 4; ++j) acc[i][j] = zero4;

    const int r0 = tid >> 2, oo = (tid & 3) * 8;   // chunk row / k-offset
    const int r1 = r0 + 64;

    for (int k0 = 0; k0 < K; k0 += 32) {
        uint4 a0 = *(const uint4*)(A  + (size_t)(m0 + r0) * K + k0 + oo);
        uint4 a1 = *(const uint4*)(A  + (size_t)(m0 + r1) * K + k0 + oo);
        uint4 b0 = *(const uint4*)(Bt + (size_t)(n0 + r0) * K + k0 + oo);
        uint4 b1 = *(const uint4*)(Bt + (size_t)(n0 + r1) * K + k0 + oo);
        __syncthreads();
        *(uint4*)&As[r0][oo] = a0;
        *(uint4*)&As[r1][oo] = a1;
        *(uint4*)&Bs[r0][oo] = b0;
        *(uint4*)&Bs[r1][oo] = b1;
        __syncthreads();

        bf16x8 af[4], bf[4];
#pragma unroll
        for (int t = 0; t < 4; ++t) af[t] = *(const bf16x8*)&As[wm * 64 + t * 16 + l15][quad * 8];
#pragma unroll
        for (int t = 0; t < 4; ++t) bf[t] = *(const bf16x8*)&Bs[wn * 64 + t * 16 + l15][quad * 8];
#pragma unroll
        for (int mt = 0; mt < 4; ++mt)
#pragma unroll
            for (int nt = 0; nt < 4; ++nt)
                acc[mt][nt] = MFMA_BF16(af[mt], bf[nt], acc[mt][nt]);
    }

    // epilogue: C/D layout col = l15 (+16*nt), row = quad*4 + r (+16*mt)
    if (MODE == 0) {
#pragma unroll
        for (int mt = 0; mt < 4; ++mt)
#pragma unroll
            for (int nt = 0; nt < 4; ++nt) {
                const int gn = n0 + wn * 64 + nt * 16 + l15;
#pragma unroll
                for (int r = 0; r < 4; ++r) {
                    const int gm = m0 + wm * 64 + mt * 16 + quad * 4 + r;
                    Cf[(size_t)gm * N + gn] = acc[mt][nt][r];
                }
            }
    } else {
        if (n0 < 1024) {            // Q: tanh -> qh[m][n], pitch 1024
#pragma unroll
            for (int mt = 0; mt < 4; ++mt)
#pragma unroll
                for (int nt = 0; nt < 4; ++nt) {
                    const int gn = n0 + wn * 64 + nt * 16 + l15;
#pragma unroll
                    for (int r = 0; r < 4; ++r) {
                        const int gm = m0 + wm * 64 + mt * 16 + quad * 4 + r;
                        qh[(size_t)gm * 1024 + gn] = f2b(tanhf(acc[mt][nt][r]));
                    }
                }
        } else if (n0 < 1280) {     // K: tanh -> kh[m][n-1024], pitch 256
#pragma unroll
            for (int mt = 0; mt < 4; ++mt)
#pragma unroll
                for (int nt = 0; nt < 4; ++nt) {
                    const int gn = n0 + wn * 64 + nt * 16 + l15 - 1024;
#pragma unroll
                    for (int r = 0; r < 4; ++r) {
                        const int gm = m0 + wm * 64 + mt * 16 + quad * 4 + r;
                        kh[(size_t)gm * 256 + gn] = f2b(tanhf(acc[mt][nt][r]));
                    }
                }
        } else {                    // V: sigmoid -> vtt[(b*4+g)*64+v][s] (transposed)
#pragma unroll
            for (int mt = 0; mt < 4; ++mt)
#pragma unroll
                for (int nt = 0; nt < 4; ++nt) {
                    const int gn = n0 + wn * 64 + nt * 16 + l15 - 1280;
                    const int g = gn >> 6, vv = gn & 63;
                    const int s0 = m0 + wm * 64 + mt * 16 + quad * 4;   // 4 consecutive s
                    const int b = s0 >> 11, sl = s0 & 2047;
                    ushort4 pk;
                    unsigned short* pp = (unsigned short*)&pk;
#pragma unroll
                    for (int r = 0; r < 4; ++r) {
                        float sv = 1.0f / (1.0f + __expf(-acc[mt][nt][r]));
                        pp[r] = f2b(sv);
                    }
                    *(ushort4*)&vtt[((size_t)(b * 4 + g) * 64 + vv) * 2048 + sl] = pk;
                }
        }
    }
}

// ---------------------------------------------------------------------------
// Barrier-free MFMA flash attention, fixed-max softmax.
// Block = 1 wave (64 threads) = (q16, h, b): 16 query rows q16*16..+15.
// Scores are bounded: s = tanh.tanh dot / 64 in (-1,1) -> softmax with fixed
// max: p = exp2(s * log2e/64), no running max / alpha rescale; l accumulated
// per-lane, reduced once at the end.
// Computes S^T = K.Q^T per 64-k tile: C-layout gives lane q=l15,
// j=nt*16+quad*4+r -> packed ushort4 P^T store to per-block LDS; PV reads
// A-frag as ds_read_b128. K/V/Q frags load straight from global (L2).
// qh [b,s,h,64] bf16, kh [b,s,g,64] bf16, vtt [b,g,v,s] bf16 (transposed).
// Epilogue fuses out_bits = e0 + ctx*(e1-e0), writes bf16 ob [b,s,h,64].
// ---------------------------------------------------------------------------
__global__ __launch_bounds__(64) void rosa_attn_mfma(
    const unsigned short* __restrict__ qh,
    const unsigned short* __restrict__ kh,
    const unsigned short* __restrict__ vtt,
    const int* __restrict__ amask,
    const float* __restrict__ emb0,
    const float* __restrict__ emb1,
    unsigned short* __restrict__ ob)
{
    __shared__ __align__(16) unsigned short Ps[16][72];   // [q_local][j], per-wave private

    const int q16 = 127 - blockIdx.x;             // descending: long blocks first
    const int h = blockIdx.y, b = blockIdx.z, g = h >> 2;
    const int lane = threadIdx.x;
    const int l15 = lane & 15, quad = lane >> 4;

    const int qg   = q16 * 16 + l15;              // this lane's q row (softmax col)
    const int qmax = q16 * 16 + 15;

    // Q B-fragment (n = q = l15, k = d = quad*8 + jj), hoisted
    const unsigned short* qrow = qh + ((size_t)(b * 2048 + q16 * 16 + l15) * 16 + h) * 64;
    const bf16x8 qf0 = *(const bf16x8*)(qrow + quad * 8);
    const bf16x8 qf1 = *(const bf16x8*)(qrow + 32 + quad * 8);

    const unsigned short* kbase = kh + (size_t)b * 2048 * 256 + g * 64;        // row stride 256
    const unsigned short* vbase = vtt + ((size_t)(b * 4 + g) * 64) * 2048;     // row stride 2048

    const f32x4 zero4 = {0.f, 0.f, 0.f, 0.f};
    f32x4 oacc[4];
#pragma unroll
    for (int t = 0; t < 4; ++t) oacc[t] = zero4;
    float psum = 0.0f;

    const float cexp = 0.0225421100f;             // log2(e)/64
    const int nkt = (q16 >> 2) + 1;

    for (int kt = 0; kt < nkt; ++kt) {
        const int k0 = kt * 64;
        const int ntmax = min(4, ((qmax - k0) >> 4) + 1);   // wave-uniform

        // ---- scores S^T = K.Q^T, one 16x16 tile per nt ----
#pragma unroll
        for (int nt = 0; nt < 4; ++nt) {
            ushort4 pk;
            if (nt < ntmax) {
                const unsigned short* krow = kbase + (size_t)(k0 + nt * 16 + l15) * 256;
                bf16x8 kf0 = *(const bf16x8*)(krow + quad * 8);
                bf16x8 kf1 = *(const bf16x8*)(krow + 32 + quad * 8);
                f32x4 sc = MFMA_BF16(kf0, qf0, zero4);
                sc = MFMA_BF16(kf1, qf1, sc);
                const int4 m4 = *(const int4*)(amask + b * 2048 + k0 + nt * 16 + quad * 4);
                const int* mm = (const int*)&m4;
                unsigned short* pp = (unsigned short*)&pk;
#pragma unroll
                for (int r = 0; r < 4; ++r) {
                    const int jg = k0 + nt * 16 + quad * 4 + r;
                    float p = __builtin_exp2f(sc[r] * cexp);
                    const bool valid = (jg <= qg) && (mm[r] != 0);
                    p = valid ? p : 0.0f;
                    psum += p;
                    pp[r] = f2b(p);
                }
            } else {
                pk.x = 0; pk.y = 0; pk.z = 0; pk.w = 0;
            }
            *(ushort4*)&Ps[l15][nt * 16 + quad * 4] = pk;   // P^T, packed along j
        }

        // ---- O += P.V (A = P[q][j] from LDS, B = V^T[v][j] from global) ----
        const bf16x8 pf0 = *(const bf16x8*)&Ps[l15][quad * 8];
        const bf16x8 pf1 = *(const bf16x8*)&Ps[l15][32 + quad * 8];
#pragma unroll
        for (int nt = 0; nt < 4; ++nt) {
            const unsigned short* vrow = vbase + (size_t)(nt * 16 + l15) * 2048 + k0;
            bf16x8 vf0 = *(const bf16x8*)(vrow + quad * 8);
            bf16x8 vf1 = *(const bf16x8*)(vrow + 32 + quad * 8);
            oacc[nt] = MFMA_BF16(pf0, vf0, oacc[nt]);
            oacc[nt] = MFMA_BF16(pf1, vf1, oacc[nt]);
        }
    }

    // ---- l: reduce per-lane partials across the 4 quads holding same q ----
    float l = psum;
    l += __shfl_xor(l, 16);
    l += __shfl_xor(l, 32);

    // epilogue: oacc lane layout row = q_local = quad*4+r, col = v = nt*16+l15
    float lq[4];
#pragma unroll
    for (int r = 0; r < 4; ++r) lq[r] = __shfl(l, quad * 4 + r);   // lane i<16 has l for q_local=i

#pragma unroll
    for (int nt = 0; nt < 4; ++nt) {
        const float e0 = emb0[h * 64 + nt * 16 + l15];
        const float e1 = emb1[h * 64 + nt * 16 + l15];
#pragma unroll
        for (int r = 0; r < 4; ++r) {
            const float ctx = oacc[nt][r] / lq[r];
            const float val = e0 + ctx * (e1 - e0);
            const size_t s_idx = (size_t)(b * 2048 + q16 * 16 + quad * 4 + r);
            ob[(s_idx * 16 + h) * 64 + nt * 16 + l15] = f2b(val);
        }
    }
}

// ---------------------------------------------------------------------------
extern "C" void kernel_launch(void* const* d_in, const int* in_sizes, int n_in,
                              void* d_out, int out_size, void* d_ws, size_t ws_size,
                              hipStream_t stream)
{
    const float* x    = (const float*)d_in[0];
    const int*   amask= (const int*)d_in[1];
    const float* Wq   = (const float*)d_in[2];
    const float* Wk   = (const float*)d_in[3];
    const float* Wv   = (const float*)d_in[4];
    const float* Wo   = (const float*)d_in[5];
    const float* emb0 = (const float*)d_in[6];
    const float* emb1 = (const float*)d_in[7];
    float* out = (float*)d_out;

    // workspace layout (38 MB total; ob aliases dead xh):
    char* base = (char*)d_ws;
    unsigned short* xh    = (unsigned short*)(base);                      // 16 MB
    unsigned short* ob    = xh;                                           // aliases xh
    unsigned short* Wqkvt = (unsigned short*)(base + (16u << 20));        // 6 MB
    unsigned short* Wot   = (unsigned short*)(base + (22u << 20));        // 4 MB
    unsigned short* qh    = (unsigned short*)(base + (26u << 20));        // 8 MB
    unsigned short* kh    = (unsigned short*)(base + (34u << 20));        // 2 MB
    unsigned short* vtt   = (unsigned short*)(base + (36u << 20));        // 2 MB

    conv_bf16<<<2048, 256, 0, stream>>>(x, xh, 4096 * 2048);
    transp_conv<<<dim3(1024 / 32, 2048 / 32), dim3(32, 8), 0, stream>>>(Wq, 2048, 1024, Wqkvt, 2048);
    transp_conv<<<dim3(256 / 32, 2048 / 32), dim3(32, 8), 0, stream>>>(Wk, 2048, 256, Wqkvt + (size_t)1024 * 2048, 2048);
    transp_conv<<<dim3(256 / 32, 2048 / 32), dim3(32, 8), 0, stream>>>(Wv, 2048, 256, Wqkvt + (size_t)1280 * 2048, 2048);
    transp_conv<<<dim3(2048 / 32, 1024 / 32), dim3(32, 8), 0, stream>>>(Wo, 1024, 2048, Wot, 1024);

    gemm_bt_mfma<1><<<dim3(12, 32), 256, 0, stream>>>(xh, Wqkvt, 4096, 1536, 2048,
                                                      nullptr, qh, kh, vtt);
    rosa_attn_mfma<<<dim3(128, 16, 2), 64, 0, stream>>>(qh, kh, vtt, amask, emb0, emb1, ob);
    gemm_bt_mfma<0><<<dim3(16, 32), 256, 0, stream>>>(ob, Wot, 4096, 2048, 1024,
                                                      out, nullptr, nullptr, nullptr);
}

// Round 4
// 261.338 us; speedup vs baseline: 1.7102x; 1.7102x over previous
//
#include <hip/hip_runtime.h>
#include <math.h>

typedef short bf16x8 __attribute__((ext_vector_type(8)));
typedef float f32x4 __attribute__((ext_vector_type(4)));

#define MFMA_BF16(A,B,C) __builtin_amdgcn_mfma_f32_16x16x32_bf16(A,B,C,0,0,0)

__device__ __forceinline__ unsigned short f2b(float x) {
    union { float f; unsigned int u; } v; v.f = x;
    unsigned int r = v.u + 0x7FFFu + ((v.u >> 16) & 1u);
    return (unsigned short)(r >> 16);
}

// ---------------------------------------------------------------------------
// fp32 -> bf16 convert (flat)
// ---------------------------------------------------------------------------
__global__ __launch_bounds__(256) void conv_bf16(const float* __restrict__ s,
                                                 unsigned short* __restrict__ d, int n)
{
    int i = blockIdx.x * blockDim.x + threadIdx.x;
    int stride = gridDim.x * blockDim.x;
    for (int idx = i * 4; idx < n; idx += stride * 4) {
        float4 v = *(const float4*)(s + idx);
        ushort4 o;
        o.x = f2b(v.x); o.y = f2b(v.y); o.z = f2b(v.z); o.w = f2b(v.w);
        *(ushort4*)(d + idx) = o;
    }
}

// ---------------------------------------------------------------------------
// fp32 [R][C] -> bf16 transposed [C][R] (dst pitch = R). R,C multiples of 32.
// ---------------------------------------------------------------------------
__global__ __launch_bounds__(256) void transp_conv(const float* __restrict__ src, int R, int C,
                                                   unsigned short* __restrict__ dst, int pitch)
{
    __shared__ float t[32][33];
    const int tx = threadIdx.x, ty = threadIdx.y;   // (32,8)
    const int c = blockIdx.x * 32 + tx;
    const int r0 = blockIdx.y * 32;
#pragma unroll
    for (int i = 0; i < 4; ++i)
        t[ty + i * 8][tx] = src[(size_t)(r0 + ty + i * 8) * C + c];
    __syncthreads();
    const int cc = blockIdx.x * 32 + ty;
#pragma unroll
    for (int i = 0; i < 4; ++i)
        dst[(size_t)(cc + i * 8) * pitch + r0 + tx] = f2b(t[tx][ty + i * 8]);
}

// ---------------------------------------------------------------------------
// bf16 MFMA GEMM, B^T input: C[M][N] = A[M][K] @ Bt[N][K]^T
// 128x128 tile, BK=32, 256 threads (4 waves, 2x2), 16x16x32 MFMA.
// MODE 0: plain fp32 store; MODE 1: fused QKV epilogue (see R2 notes).
// ---------------------------------------------------------------------------
template <int MODE>
__global__ __launch_bounds__(256) void gemm_bt_mfma(
    const unsigned short* __restrict__ A,
    const unsigned short* __restrict__ Bt,
    int M, int N, int K,
    float* __restrict__ Cf,
    unsigned short* __restrict__ qh,
    unsigned short* __restrict__ kh,
    unsigned short* __restrict__ vtt)
{
    __shared__ __align__(16) unsigned short As[128][40];
    __shared__ __align__(16) unsigned short Bs[128][40];

    const int tid = threadIdx.x;
    const int w = tid >> 6, lane = tid & 63, l15 = lane & 15, quad = lane >> 4;
    const int wm = w & 1, wn = w >> 1;
    const int m0 = blockIdx.y * 128, n0 = blockIdx.x * 128;

    f32x4 acc[4][4];
    const f32x4 zero4 = {0.f, 0.f, 0.f, 0.f};
#pragma unroll
    for (int i = 0; i < 4; ++i)
#pragma unroll
        for (int j = 0; j < 4; ++j) acc[i][j] = zero4;

    const int r0 = tid >> 2, oo = (tid & 3) * 8;
    const int r1 = r0 + 64;

    for (int k0 = 0; k0 < K; k0 += 32) {
        uint4 a0 = *(const uint4*)(A  + (size_t)(m0 + r0) * K + k0 + oo);
        uint4 a1 = *(const uint4*)(A  + (size_t)(m0 + r1) * K + k0 + oo);
        uint4 b0 = *(const uint4*)(Bt + (size_t)(n0 + r0) * K + k0 + oo);
        uint4 b1 = *(const uint4*)(Bt + (size_t)(n0 + r1) * K + k0 + oo);
        __syncthreads();
        *(uint4*)&As[r0][oo] = a0;
        *(uint4*)&As[r1][oo] = a1;
        *(uint4*)&Bs[r0][oo] = b0;
        *(uint4*)&Bs[r1][oo] = b1;
        __syncthreads();

        bf16x8 af[4], bf[4];
#pragma unroll
        for (int t = 0; t < 4; ++t) af[t] = *(const bf16x8*)&As[wm * 64 + t * 16 + l15][quad * 8];
#pragma unroll
        for (int t = 0; t < 4; ++t) bf[t] = *(const bf16x8*)&Bs[wn * 64 + t * 16 + l15][quad * 8];
#pragma unroll
        for (int mt = 0; mt < 4; ++mt)
#pragma unroll
            for (int nt = 0; nt < 4; ++nt)
                acc[mt][nt] = MFMA_BF16(af[mt], bf[nt], acc[mt][nt]);
    }

    if (MODE == 0) {
#pragma unroll
        for (int mt = 0; mt < 4; ++mt)
#pragma unroll
            for (int nt = 0; nt < 4; ++nt) {
                const int gn = n0 + wn * 64 + nt * 16 + l15;
#pragma unroll
                for (int r = 0; r < 4; ++r) {
                    const int gm = m0 + wm * 64 + mt * 16 + quad * 4 + r;
                    Cf[(size_t)gm * N + gn] = acc[mt][nt][r];
                }
            }
    } else {
        if (n0 < 1024) {
#pragma unroll
            for (int mt = 0; mt < 4; ++mt)
#pragma unroll
                for (int nt = 0; nt < 4; ++nt) {
                    const int gn = n0 + wn * 64 + nt * 16 + l15;
#pragma unroll
                    for (int r = 0; r < 4; ++r) {
                        const int gm = m0 + wm * 64 + mt * 16 + quad * 4 + r;
                        qh[(size_t)gm * 1024 + gn] = f2b(tanhf(acc[mt][nt][r]));
                    }
                }
        } else if (n0 < 1280) {
#pragma unroll
            for (int mt = 0; mt < 4; ++mt)
#pragma unroll
                for (int nt = 0; nt < 4; ++nt) {
                    const int gn = n0 + wn * 64 + nt * 16 + l15 - 1024;
#pragma unroll
                    for (int r = 0; r < 4; ++r) {
                        const int gm = m0 + wm * 64 + mt * 16 + quad * 4 + r;
                        kh[(size_t)gm * 256 + gn] = f2b(tanhf(acc[mt][nt][r]));
                    }
                }
        } else {
#pragma unroll
            for (int mt = 0; mt < 4; ++mt)
#pragma unroll
                for (int nt = 0; nt < 4; ++nt) {
                    const int gn = n0 + wn * 64 + nt * 16 + l15 - 1280;
                    const int g = gn >> 6, vv = gn & 63;
                    const int s0 = m0 + wm * 64 + mt * 16 + quad * 4;
                    const int b = s0 >> 11, sl = s0 & 2047;
                    ushort4 pk;
                    unsigned short* pp = (unsigned short*)&pk;
#pragma unroll
                    for (int r = 0; r < 4; ++r) {
                        float sv = 1.0f / (1.0f + __expf(-acc[mt][nt][r]));
                        pp[r] = f2b(sv);
                    }
                    *(ushort4*)&vtt[((size_t)(b * 4 + g) * 64 + vv) * 2048 + sl] = pk;
                }
        }
    }
}

// ---------------------------------------------------------------------------
// MFMA flash attention, fixed-max softmax, pipelined double-buffered staging.
// Block = (pair, h, b), 4 waves; paired q-tiles (qt, 31-qt) -> uniform 33
// k-tiles/block. Wave w owns q-rows q0+w*16..+15.
// Scores bounded (|s|<1) -> p = exp2(s*log2e/64), no running max/alpha;
// per-lane psum, reduced once per half.
// S^T = K.Q^T per 16x16 sub-tile: lane q=l15, j=quad*4+r -> packed ushort4
// P^T stores to per-wave-private Ps; PV A-frag = ds_read_b128.
// K/V cooperatively staged global->LDS (coalesced), double-buffered,
// next tile's loads issued before current tile's compute; ONE barrier/tile.
// ---------------------------------------------------------------------------
__global__ __launch_bounds__(256) void rosa_attn_mfma(
    const unsigned short* __restrict__ qh,
    const unsigned short* __restrict__ kh,
    const unsigned short* __restrict__ vtt,
    const int* __restrict__ amask,
    const float* __restrict__ emb0,
    const float* __restrict__ emb1,
    unsigned short* __restrict__ ob)
{
    __shared__ __align__(16) unsigned short Ks[2][64][72];   // [buf][k-row][d]
    __shared__ __align__(16) unsigned short Vs[2][64][72];   // [buf][v][j]
    __shared__ __align__(16) unsigned short Ps[4][16][72];   // [wave][q][j]
    __shared__ float Mskf[2][64];

    const int pairI = blockIdx.x;                 // 0..15
    const int h = blockIdx.y, b = blockIdx.z, g = h >> 2;
    const int tid = threadIdx.x;
    const int w = tid >> 6, lane = tid & 63, l15 = lane & 15, quad = lane >> 4;

    // staging indices: 512 uint4 per 64x64 bf16 tile, 2 per thread
    const int srow0 = tid >> 3,        soff0 = (tid & 7) * 8;
    const int srow1 = (tid + 256) >> 3, soff1 = ((tid + 256) & 7) * 8;

    const unsigned short* kbase = kh + (size_t)b * 2048 * 256 + g * 64;     // row stride 256
    const unsigned short* vbase = vtt + ((size_t)(b * 4 + g) * 64) * 2048;  // row stride 2048

    const f32x4 zero4 = {0.f, 0.f, 0.f, 0.f};
    const float cexp = 0.0225421100f;             // log2(e)/64

    for (int half = 0; half < 2; ++half) {
        const int qt = (half == 0) ? pairI : 31 - pairI;
        const int q0 = qt * 64;
        const int nkt = qt + 1;
        const int qg = q0 + w * 16 + l15;         // this lane's q row

        // Q B-fragment (n = q = l15, k = d), per wave
        const unsigned short* qrow = qh + ((size_t)(b * 2048 + q0 + w * 16 + l15) * 16 + h) * 64;
        const bf16x8 qf0 = *(const bf16x8*)(qrow + quad * 8);
        const bf16x8 qf1 = *(const bf16x8*)(qrow + 32 + quad * 8);

        f32x4 oacc[4];
#pragma unroll
        for (int t = 0; t < 4; ++t) oacc[t] = zero4;
        float psum = 0.0f;

        // ---- prologue: stage tile 0 into buffer 0 ----
        __syncthreads();   // protect LDS from previous half's readers
        {
            uint4 k0r = *(const uint4*)(kbase + (size_t)srow0 * 256 + soff0);
            uint4 k1r = *(const uint4*)(kbase + (size_t)srow1 * 256 + soff1);
            uint4 v0r = *(const uint4*)(vbase + (size_t)srow0 * 2048 + soff0);
            uint4 v1r = *(const uint4*)(vbase + (size_t)srow1 * 2048 + soff1);
            int mr = (tid < 64) ? amask[b * 2048 + tid] : 0;
            *(uint4*)&Ks[0][srow0][soff0] = k0r;
            *(uint4*)&Ks[0][srow1][soff1] = k1r;
            *(uint4*)&Vs[0][srow0][soff0] = v0r;
            *(uint4*)&Vs[0][srow1][soff1] = v1r;
            if (tid < 64) Mskf[0][tid] = mr ? 1.0f : 0.0f;
        }
        __syncthreads();

        int cb = 0;
        for (int kt = 0; kt < nkt; ++kt) {
            const bool haveNext = (kt + 1 < nkt);
            uint4 k0r, k1r, v0r, v1r;
            int mr = 0;
            if (haveNext) {
                const int kn = (kt + 1) * 64;
                k0r = *(const uint4*)(kbase + (size_t)(kn + srow0) * 256 + soff0);
                k1r = *(const uint4*)(kbase + (size_t)(kn + srow1) * 256 + soff1);
                v0r = *(const uint4*)(vbase + (size_t)srow0 * 2048 + kn + soff0);
                v1r = *(const uint4*)(vbase + (size_t)srow1 * 2048 + kn + soff1);
                if (tid < 64) mr = amask[b * 2048 + kn + tid];
            }

            // ---- compute tile kt from LDS[cb] ----
            const int k0 = kt * 64;
            const bool diag = (kt == qt);
            const int ntlim = diag ? (w + 1) : 4;

#pragma unroll
            for (int nt = 0; nt < 4; ++nt) {
                ushort4 pk;
                if (nt < ntlim) {
                    bf16x8 kf0 = *(const bf16x8*)&Ks[cb][nt * 16 + l15][quad * 8];
                    bf16x8 kf1 = *(const bf16x8*)&Ks[cb][nt * 16 + l15][32 + quad * 8];
                    f32x4 sc = MFMA_BF16(kf0, qf0, zero4);
                    sc = MFMA_BF16(kf1, qf1, sc);
                    float4 mv = *(const float4*)&Mskf[cb][nt * 16 + quad * 4];
                    const float* mvp = (const float*)&mv;
                    unsigned short* pp = (unsigned short*)&pk;
#pragma unroll
                    for (int r = 0; r < 4; ++r) {
                        float p = __builtin_exp2f(sc[r] * cexp) * mvp[r];
                        if (diag) {
                            const int jg = k0 + nt * 16 + quad * 4 + r;
                            p = (jg <= qg) ? p : 0.0f;
                        }
                        psum += p;
                        pp[r] = f2b(p);
                    }
                } else {
                    pk.x = 0; pk.y = 0; pk.z = 0; pk.w = 0;
                }
                *(ushort4*)&Ps[w][l15][nt * 16 + quad * 4] = pk;
            }

            // PV: O += P.V
            const bf16x8 pf0 = *(const bf16x8*)&Ps[w][l15][quad * 8];
            const bf16x8 pf1 = *(const bf16x8*)&Ps[w][l15][32 + quad * 8];
#pragma unroll
            for (int nt = 0; nt < 4; ++nt) {
                bf16x8 vf0 = *(const bf16x8*)&Vs[cb][nt * 16 + l15][quad * 8];
                bf16x8 vf1 = *(const bf16x8*)&Vs[cb][nt * 16 + l15][32 + quad * 8];
                oacc[nt] = MFMA_BF16(pf0, vf0, oacc[nt]);
                oacc[nt] = MFMA_BF16(pf1, vf1, oacc[nt]);
            }

            if (haveNext) {
                // safe: last reads of buffer cb^1 completed before the barrier
                // that ended iteration kt-1 (or the prologue barrier for kt=0)
                const int nb = cb ^ 1;
                *(uint4*)&Ks[nb][srow0][soff0] = k0r;
                *(uint4*)&Ks[nb][srow1][soff1] = k1r;
                *(uint4*)&Vs[nb][srow0][soff0] = v0r;
                *(uint4*)&Vs[nb][srow1][soff1] = v1r;
                if (tid < 64) Mskf[nb][tid] = mr ? 1.0f : 0.0f;
                __syncthreads();
                cb = nb;
            }
        }

        // ---- l reduction: sum partials across the 4 quads holding same q ----
        float l = psum;
        l += __shfl_xor(l, 16);
        l += __shfl_xor(l, 32);
        float lq[4];
#pragma unroll
        for (int r = 0; r < 4; ++r) lq[r] = __shfl(l, quad * 4 + r);

        // epilogue: oacc row = q_local = quad*4+r, col = v = nt*16+l15
#pragma unroll
        for (int nt = 0; nt < 4; ++nt) {
            const float e0 = emb0[h * 64 + nt * 16 + l15];
            const float e1 = emb1[h * 64 + nt * 16 + l15];
#pragma unroll
            for (int r = 0; r < 4; ++r) {
                const float ctx = oacc[nt][r] / lq[r];
                const float val = e0 + ctx * (e1 - e0);
                const size_t s_idx = (size_t)(b * 2048 + q0 + w * 16 + quad * 4 + r);
                ob[(s_idx * 16 + h) * 64 + nt * 16 + l15] = f2b(val);
            }
        }
    }
}

// ---------------------------------------------------------------------------
extern "C" void kernel_launch(void* const* d_in, const int* in_sizes, int n_in,
                              void* d_out, int out_size, void* d_ws, size_t ws_size,
                              hipStream_t stream)
{
    const float* x    = (const float*)d_in[0];
    const int*   amask= (const int*)d_in[1];
    const float* Wq   = (const float*)d_in[2];
    const float* Wk   = (const float*)d_in[3];
    const float* Wv   = (const float*)d_in[4];
    const float* Wo   = (const float*)d_in[5];
    const float* emb0 = (const float*)d_in[6];
    const float* emb1 = (const float*)d_in[7];
    float* out = (float*)d_out;

    char* base = (char*)d_ws;
    unsigned short* xh    = (unsigned short*)(base);                      // 16 MB
    unsigned short* ob    = xh;                                           // aliases xh
    unsigned short* Wqkvt = (unsigned short*)(base + (16u << 20));        // 6 MB
    unsigned short* Wot   = (unsigned short*)(base + (22u << 20));        // 4 MB
    unsigned short* qh    = (unsigned short*)(base + (26u << 20));        // 8 MB
    unsigned short* kh    = (unsigned short*)(base + (34u << 20));        // 2 MB
    unsigned short* vtt   = (unsigned short*)(base + (36u << 20));        // 2 MB

    conv_bf16<<<2048, 256, 0, stream>>>(x, xh, 4096 * 2048);
    transp_conv<<<dim3(1024 / 32, 2048 / 32), dim3(32, 8), 0, stream>>>(Wq, 2048, 1024, Wqkvt, 2048);
    transp_conv<<<dim3(256 / 32, 2048 / 32), dim3(32, 8), 0, stream>>>(Wk, 2048, 256, Wqkvt + (size_t)1024 * 2048, 2048);
    transp_conv<<<dim3(256 / 32, 2048 / 32), dim3(32, 8), 0, stream>>>(Wv, 2048, 256, Wqkvt + (size_t)1280 * 2048, 2048);
    transp_conv<<<dim3(2048 / 32, 1024 / 32), dim3(32, 8), 0, stream>>>(Wo, 1024, 2048, Wot, 1024);

    gemm_bt_mfma<1><<<dim3(12, 32), 256, 0, stream>>>(xh, Wqkvt, 4096, 1536, 2048,
                                                      nullptr, qh, kh, vtt);
    rosa_attn_mfma<<<dim3(16, 16, 2), 256, 0, stream>>>(qh, kh, vtt, amask, emb0, emb1, ob);
    gemm_bt_mfma<0><<<dim3(16, 32), 256, 0, stream>>>(ob, Wot, 4096, 2048, 1024,
                                                      out, nullptr, nullptr, nullptr);
}

// Round 5
// 253.043 us; speedup vs baseline: 1.7663x; 1.0328x over previous
//
#include <hip/hip_runtime.h>
#include <math.h>

typedef short bf16x8 __attribute__((ext_vector_type(8)));
typedef float f32x4 __attribute__((ext_vector_type(4)));

#define MFMA_BF16(A,B,C) __builtin_amdgcn_mfma_f32_16x16x32_bf16(A,B,C,0,0,0)

__device__ __forceinline__ unsigned short f2b(float x) {
    union { float f; unsigned int u; } v; v.f = x;
    unsigned int r = v.u + 0x7FFFu + ((v.u >> 16) & 1u);
    return (unsigned short)(r >> 16);
}

// async global->LDS DMA, 16B per lane; LDS dest = wave-uniform base + lane*16
__device__ __forceinline__ void gload16(const unsigned short* g, unsigned short* l) {
    __builtin_amdgcn_global_load_lds(
        (const __attribute__((address_space(1))) unsigned int*)(g),
        (__attribute__((address_space(3))) unsigned int*)(l),
        16, 0, 0);
}

// ---------------------------------------------------------------------------
// fp32 -> bf16 convert (flat)
// ---------------------------------------------------------------------------
__global__ __launch_bounds__(256) void conv_bf16(const float* __restrict__ s,
                                                 unsigned short* __restrict__ d, int n)
{
    int i = blockIdx.x * blockDim.x + threadIdx.x;
    int stride = gridDim.x * blockDim.x;
    for (int idx = i * 4; idx < n; idx += stride * 4) {
        float4 v = *(const float4*)(s + idx);
        ushort4 o;
        o.x = f2b(v.x); o.y = f2b(v.y); o.z = f2b(v.z); o.w = f2b(v.w);
        *(ushort4*)(d + idx) = o;
    }
}

// ---------------------------------------------------------------------------
// Fused weight transpose+convert: Wq|Wk|Wv (fp32, [2048][C]) -> bf16 [C][2048]
// packed into one dst with per-matrix col offsets. grid.x: 0-31 Wq, 32-39 Wk,
// 40-47 Wv. Also used standalone for Wo.
// ---------------------------------------------------------------------------
__global__ __launch_bounds__(256) void transp_conv_qkv(const float* __restrict__ Wq,
                                                       const float* __restrict__ Wk,
                                                       const float* __restrict__ Wv,
                                                       unsigned short* __restrict__ dst)
{
    __shared__ float t[32][33];
    const int tx = threadIdx.x, ty = threadIdx.y;   // (32,8)
    int bx = blockIdx.x;
    const float* src; int C, cb, dco;
    if (bx < 32)      { src = Wq; C = 1024; cb = bx;      dco = 0; }
    else if (bx < 40) { src = Wk; C = 256;  cb = bx - 32; dco = 1024; }
    else              { src = Wv; C = 256;  cb = bx - 40; dco = 1280; }
    const int c = cb * 32 + tx;
    const int r0 = blockIdx.y * 32;
#pragma unroll
    for (int i = 0; i < 4; ++i)
        t[ty + i * 8][tx] = src[(size_t)(r0 + ty + i * 8) * C + c];
    __syncthreads();
    const int cc = cb * 32 + ty;
#pragma unroll
    for (int i = 0; i < 4; ++i)
        dst[(size_t)(dco + cc + i * 8) * 2048 + r0 + tx] = f2b(t[tx][ty + i * 8]);
}

__global__ __launch_bounds__(256) void transp_conv(const float* __restrict__ src, int R, int C,
                                                   unsigned short* __restrict__ dst, int pitch)
{
    __shared__ float t[32][33];
    const int tx = threadIdx.x, ty = threadIdx.y;
    const int c = blockIdx.x * 32 + tx;
    const int r0 = blockIdx.y * 32;
#pragma unroll
    for (int i = 0; i < 4; ++i)
        t[ty + i * 8][tx] = src[(size_t)(r0 + ty + i * 8) * C + c];
    __syncthreads();
    const int cc = blockIdx.x * 32 + ty;
#pragma unroll
    for (int i = 0; i < 4; ++i)
        dst[(size_t)(cc + i * 8) * pitch + r0 + tx] = f2b(t[tx][ty + i * 8]);
}

// ---------------------------------------------------------------------------
// bf16 MFMA GEMM, B^T input, m97 structure: C[M][N] = A[M][K] @ Bt[N][K]^T
// 128x128 tile, BK=32, 256 threads (4 waves 2x2), global_load_lds dwordx4
// staging into UNPADDED LDS [128][32] (DMA lands at base + lane*16),
// fragments via ds_read_b128, 16 MFMA / iter, 2 barriers / iter.
// MODE 0: plain fp32 store; MODE 1: fused QKV epilogue.
// ---------------------------------------------------------------------------
template <int MODE>
__global__ __launch_bounds__(256) void gemm_bt_mfma(
    const unsigned short* __restrict__ A,
    const unsigned short* __restrict__ Bt,
    int M, int N, int K,
    float* __restrict__ Cf,
    unsigned short* __restrict__ qh,
    unsigned short* __restrict__ kh,
    unsigned short* __restrict__ vtt)
{
    __shared__ __align__(16) unsigned short As[128 * 32];   // unpadded, 8 KB
    __shared__ __align__(16) unsigned short Bs[128 * 32];

    const int tid = threadIdx.x;
    const int w = tid >> 6, lane = tid & 63, l15 = lane & 15, quad = lane >> 4;
    const int wm = w & 1, wn = w >> 1;
    const int m0 = blockIdx.y * 128, n0 = blockIdx.x * 128;

    f32x4 acc[4][4];
    const f32x4 zero4 = {0.f, 0.f, 0.f, 0.f};
#pragma unroll
    for (int i = 0; i < 4; ++i)
#pragma unroll
        for (int j = 0; j < 4; ++j) acc[i][j] = zero4;

    // DMA staging: wave w stages rows w*32..w*32+31 of each tile (2 issues).
    // lane i -> row base + (i>>2), 16B chunk (i&3); LDS = base + lane*16.
    const int strow = w * 32 + (lane >> 2);
    const int stoff = (lane & 3) * 8;                       // bf16 elements
    const unsigned short* Ag = A  + (size_t)(m0 + strow) * K + stoff;
    const unsigned short* Bg = Bt + (size_t)(n0 + strow) * K + stoff;
    unsigned short* AsW = &As[(w * 32) * 32];               // wave-uniform
    unsigned short* BsW = &Bs[(w * 32) * 32];

    for (int k0 = 0; k0 < K; k0 += 32) {
        __syncthreads();                    // prev iter's ds_reads done
        gload16(Ag, AsW);
        gload16(Ag + (size_t)16 * K, AsW + 16 * 32);
        gload16(Bg, BsW);
        gload16(Bg + (size_t)16 * K, BsW + 16 * 32);
        Ag += 32; Bg += 32;
        __syncthreads();                    // vmcnt(0) drain -> tile visible

        bf16x8 af[4], bf[4];
#pragma unroll
        for (int t = 0; t < 4; ++t)
            af[t] = *(const bf16x8*)&As[(wm * 64 + t * 16 + l15) * 32 + quad * 8];
#pragma unroll
        for (int t = 0; t < 4; ++t)
            bf[t] = *(const bf16x8*)&Bs[(wn * 64 + t * 16 + l15) * 32 + quad * 8];
#pragma unroll
        for (int mt = 0; mt < 4; ++mt)
#pragma unroll
            for (int nt = 0; nt < 4; ++nt)
                acc[mt][nt] = MFMA_BF16(af[mt], bf[nt], acc[mt][nt]);
    }

    // epilogue: C/D layout col = l15 (+16*nt), row = quad*4 + r (+16*mt)
    if (MODE == 0) {
#pragma unroll
        for (int mt = 0; mt < 4; ++mt)
#pragma unroll
            for (int nt = 0; nt < 4; ++nt) {
                const int gn = n0 + wn * 64 + nt * 16 + l15;
#pragma unroll
                for (int r = 0; r < 4; ++r) {
                    const int gm = m0 + wm * 64 + mt * 16 + quad * 4 + r;
                    Cf[(size_t)gm * N + gn] = acc[mt][nt][r];
                }
            }
    } else {
        if (n0 < 1024) {            // Q: tanh -> qh[m][n], pitch 1024
#pragma unroll
            for (int mt = 0; mt < 4; ++mt)
#pragma unroll
                for (int nt = 0; nt < 4; ++nt) {
                    const int gn = n0 + wn * 64 + nt * 16 + l15;
#pragma unroll
                    for (int r = 0; r < 4; ++r) {
                        const int gm = m0 + wm * 64 + mt * 16 + quad * 4 + r;
                        qh[(size_t)gm * 1024 + gn] = f2b(tanhf(acc[mt][nt][r]));
                    }
                }
        } else if (n0 < 1280) {     // K: tanh -> kh[m][n-1024], pitch 256
#pragma unroll
            for (int mt = 0; mt < 4; ++mt)
#pragma unroll
                for (int nt = 0; nt < 4; ++nt) {
                    const int gn = n0 + wn * 64 + nt * 16 + l15 - 1024;
#pragma unroll
                    for (int r = 0; r < 4; ++r) {
                        const int gm = m0 + wm * 64 + mt * 16 + quad * 4 + r;
                        kh[(size_t)gm * 256 + gn] = f2b(tanhf(acc[mt][nt][r]));
                    }
                }
        } else {                    // V: sigmoid -> vtt[(b*4+g)*64+v][s]
#pragma unroll
            for (int mt = 0; mt < 4; ++mt)
#pragma unroll
                for (int nt = 0; nt < 4; ++nt) {
                    const int gn = n0 + wn * 64 + nt * 16 + l15 - 1280;
                    const int g = gn >> 6, vv = gn & 63;
                    const int s0 = m0 + wm * 64 + mt * 16 + quad * 4;
                    const int b = s0 >> 11, sl = s0 & 2047;
                    ushort4 pk;
                    unsigned short* pp = (unsigned short*)&pk;
#pragma unroll
                    for (int r = 0; r < 4; ++r) {
                        float sv = 1.0f / (1.0f + __expf(-acc[mt][nt][r]));
                        pp[r] = f2b(sv);
                    }
                    *(ushort4*)&vtt[((size_t)(b * 4 + g) * 64 + vv) * 2048 + sl] = pk;
                }
        }
    }
}

// ---------------------------------------------------------------------------
// MFMA flash attention, fixed-max softmax, pipelined double-buffered staging.
// (unchanged from R4 — see notes there)
// ---------------------------------------------------------------------------
__global__ __launch_bounds__(256) void rosa_attn_mfma(
    const unsigned short* __restrict__ qh,
    const unsigned short* __restrict__ kh,
    const unsigned short* __restrict__ vtt,
    const int* __restrict__ amask,
    const float* __restrict__ emb0,
    const float* __restrict__ emb1,
    unsigned short* __restrict__ ob)
{
    __shared__ __align__(16) unsigned short Ks[2][64][72];
    __shared__ __align__(16) unsigned short Vs[2][64][72];
    __shared__ __align__(16) unsigned short Ps[4][16][72];
    __shared__ float Mskf[2][64];

    const int pairI = blockIdx.x;
    const int h = blockIdx.y, b = blockIdx.z, g = h >> 2;
    const int tid = threadIdx.x;
    const int w = tid >> 6, lane = tid & 63, l15 = lane & 15, quad = lane >> 4;

    const int srow0 = tid >> 3,         soff0 = (tid & 7) * 8;
    const int srow1 = (tid + 256) >> 3, soff1 = ((tid + 256) & 7) * 8;

    const unsigned short* kbase = kh + (size_t)b * 2048 * 256 + g * 64;
    const unsigned short* vbase = vtt + ((size_t)(b * 4 + g) * 64) * 2048;

    const f32x4 zero4 = {0.f, 0.f, 0.f, 0.f};
    const float cexp = 0.0225421100f;             // log2(e)/64

    for (int half = 0; half < 2; ++half) {
        const int qt = (half == 0) ? pairI : 31 - pairI;
        const int q0 = qt * 64;
        const int nkt = qt + 1;
        const int qg = q0 + w * 16 + l15;

        const unsigned short* qrow = qh + ((size_t)(b * 2048 + q0 + w * 16 + l15) * 16 + h) * 64;
        const bf16x8 qf0 = *(const bf16x8*)(qrow + quad * 8);
        const bf16x8 qf1 = *(const bf16x8*)(qrow + 32 + quad * 8);

        f32x4 oacc[4];
#pragma unroll
        for (int t = 0; t < 4; ++t) oacc[t] = zero4;
        float psum = 0.0f;

        __syncthreads();
        {
            uint4 k0r = *(const uint4*)(kbase + (size_t)srow0 * 256 + soff0);
            uint4 k1r = *(const uint4*)(kbase + (size_t)srow1 * 256 + soff1);
            uint4 v0r = *(const uint4*)(vbase + (size_t)srow0 * 2048 + soff0);
            uint4 v1r = *(const uint4*)(vbase + (size_t)srow1 * 2048 + soff1);
            int mr = (tid < 64) ? amask[b * 2048 + tid] : 0;
            *(uint4*)&Ks[0][srow0][soff0] = k0r;
            *(uint4*)&Ks[0][srow1][soff1] = k1r;
            *(uint4*)&Vs[0][srow0][soff0] = v0r;
            *(uint4*)&Vs[0][srow1][soff1] = v1r;
            if (tid < 64) Mskf[0][tid] = mr ? 1.0f : 0.0f;
        }
        __syncthreads();

        int cb = 0;
        for (int kt = 0; kt < nkt; ++kt) {
            const bool haveNext = (kt + 1 < nkt);
            uint4 k0r, k1r, v0r, v1r;
            int mr = 0;
            if (haveNext) {
                const int kn = (kt + 1) * 64;
                k0r = *(const uint4*)(kbase + (size_t)(kn + srow0) * 256 + soff0);
                k1r = *(const uint4*)(kbase + (size_t)(kn + srow1) * 256 + soff1);
                v0r = *(const uint4*)(vbase + (size_t)srow0 * 2048 + kn + soff0);
                v1r = *(const uint4*)(vbase + (size_t)srow1 * 2048 + kn + soff1);
                if (tid < 64) mr = amask[b * 2048 + kn + tid];
            }

            const int k0 = kt * 64;
            const bool diag = (kt == qt);
            const int ntlim = diag ? (w + 1) : 4;

#pragma unroll
            for (int nt = 0; nt < 4; ++nt) {
                ushort4 pk;
                if (nt < ntlim) {
                    bf16x8 kf0 = *(const bf16x8*)&Ks[cb][nt * 16 + l15][quad * 8];
                    bf16x8 kf1 = *(const bf16x8*)&Ks[cb][nt * 16 + l15][32 + quad * 8];
                    f32x4 sc = MFMA_BF16(kf0, qf0, zero4);
                    sc = MFMA_BF16(kf1, qf1, sc);
                    float4 mv = *(const float4*)&Mskf[cb][nt * 16 + quad * 4];
                    const float* mvp = (const float*)&mv;
                    unsigned short* pp = (unsigned short*)&pk;
#pragma unroll
                    for (int r = 0; r < 4; ++r) {
                        float p = __builtin_exp2f(sc[r] * cexp) * mvp[r];
                        if (diag) {
                            const int jg = k0 + nt * 16 + quad * 4 + r;
                            p = (jg <= qg) ? p : 0.0f;
                        }
                        psum += p;
                        pp[r] = f2b(p);
                    }
                } else {
                    pk.x = 0; pk.y = 0; pk.z = 0; pk.w = 0;
                }
                *(ushort4*)&Ps[w][l15][nt * 16 + quad * 4] = pk;
            }

            const bf16x8 pf0 = *(const bf16x8*)&Ps[w][l15][quad * 8];
            const bf16x8 pf1 = *(const bf16x8*)&Ps[w][l15][32 + quad * 8];
#pragma unroll
            for (int nt = 0; nt < 4; ++nt) {
                bf16x8 vf0 = *(const bf16x8*)&Vs[cb][nt * 16 + l15][quad * 8];
                bf16x8 vf1 = *(const bf16x8*)&Vs[cb][nt * 16 + l15][32 + quad * 8];
                oacc[nt] = MFMA_BF16(pf0, vf0, oacc[nt]);
                oacc[nt] = MFMA_BF16(pf1, vf1, oacc[nt]);
            }

            if (haveNext) {
                const int nb = cb ^ 1;
                *(uint4*)&Ks[nb][srow0][soff0] = k0r;
                *(uint4*)&Ks[nb][srow1][soff1] = k1r;
                *(uint4*)&Vs[nb][srow0][soff0] = v0r;
                *(uint4*)&Vs[nb][srow1][soff1] = v1r;
                if (tid < 64) Mskf[nb][tid] = mr ? 1.0f : 0.0f;
                __syncthreads();
                cb = nb;
            }
        }

        float l = psum;
        l += __shfl_xor(l, 16);
        l += __shfl_xor(l, 32);
        float lq[4];
#pragma unroll
        for (int r = 0; r < 4; ++r) lq[r] = __shfl(l, quad * 4 + r);

#pragma unroll
        for (int nt = 0; nt < 4; ++nt) {
            const float e0 = emb0[h * 64 + nt * 16 + l15];
            const float e1 = emb1[h * 64 + nt * 16 + l15];
#pragma unroll
            for (int r = 0; r < 4; ++r) {
                const float ctx = oacc[nt][r] / lq[r];
                const float val = e0 + ctx * (e1 - e0);
                const size_t s_idx = (size_t)(b * 2048 + q0 + w * 16 + quad * 4 + r);
                ob[(s_idx * 16 + h) * 64 + nt * 16 + l15] = f2b(val);
            }
        }
    }
}

// ---------------------------------------------------------------------------
extern "C" void kernel_launch(void* const* d_in, const int* in_sizes, int n_in,
                              void* d_out, int out_size, void* d_ws, size_t ws_size,
                              hipStream_t stream)
{
    const float* x    = (const float*)d_in[0];
    const int*   amask= (const int*)d_in[1];
    const float* Wq   = (const float*)d_in[2];
    const float* Wk   = (const float*)d_in[3];
    const float* Wv   = (const float*)d_in[4];
    const float* Wo   = (const float*)d_in[5];
    const float* emb0 = (const float*)d_in[6];
    const float* emb1 = (const float*)d_in[7];
    float* out = (float*)d_out;

    char* base = (char*)d_ws;
    unsigned short* xh    = (unsigned short*)(base);                      // 16 MB
    unsigned short* ob    = xh;                                           // aliases xh
    unsigned short* Wqkvt = (unsigned short*)(base + (16u << 20));        // 6 MB
    unsigned short* Wot   = (unsigned short*)(base + (22u << 20));        // 4 MB
    unsigned short* qh    = (unsigned short*)(base + (26u << 20));        // 8 MB
    unsigned short* kh    = (unsigned short*)(base + (34u << 20));        // 2 MB
    unsigned short* vtt   = (unsigned short*)(base + (36u << 20));        // 2 MB

    conv_bf16<<<2048, 256, 0, stream>>>(x, xh, 4096 * 2048);
    transp_conv_qkv<<<dim3(48, 64), dim3(32, 8), 0, stream>>>(Wq, Wk, Wv, Wqkvt);
    transp_conv<<<dim3(64, 32), dim3(32, 8), 0, stream>>>(Wo, 1024, 2048, Wot, 1024);

    gemm_bt_mfma<1><<<dim3(12, 32), 256, 0, stream>>>(xh, Wqkvt, 4096, 1536, 2048,
                                                      nullptr, qh, kh, vtt);
    rosa_attn_mfma<<<dim3(16, 16, 2), 256, 0, stream>>>(qh, kh, vtt, amask, emb0, emb1, ob);
    gemm_bt_mfma<0><<<dim3(16, 32), 256, 0, stream>>>(ob, Wot, 4096, 2048, 1024,
                                                      out, nullptr, nullptr, nullptr);
}

// Round 6
// 246.727 us; speedup vs baseline: 1.8115x; 1.0256x over previous
//
#include <hip/hip_runtime.h>
#include <math.h>

typedef short bf16x8 __attribute__((ext_vector_type(8)));
typedef float f32x4 __attribute__((ext_vector_type(4)));

#define MFMA_BF16(A,B,C) __builtin_amdgcn_mfma_f32_16x16x32_bf16(A,B,C,0,0,0)

__device__ __forceinline__ unsigned short f2b(float x) {
    union { float f; unsigned int u; } v; v.f = x;
    unsigned int r = v.u + 0x7FFFu + ((v.u >> 16) & 1u);
    return (unsigned short)(r >> 16);
}

// async global->LDS DMA, 16B per lane; LDS dest = wave-uniform base + lane*16
__device__ __forceinline__ void gload16(const unsigned short* g, unsigned short* l) {
    __builtin_amdgcn_global_load_lds(
        (const __attribute__((address_space(1))) unsigned int*)(g),
        (__attribute__((address_space(3))) unsigned int*)(l),
        16, 0, 0);
}

// ---------------------------------------------------------------------------
// fp32 -> bf16 convert (flat)
// ---------------------------------------------------------------------------
__global__ __launch_bounds__(256) void conv_bf16(const float* __restrict__ s,
                                                 unsigned short* __restrict__ d, int n)
{
    int i = blockIdx.x * blockDim.x + threadIdx.x;
    int stride = gridDim.x * blockDim.x;
    for (int idx = i * 4; idx < n; idx += stride * 4) {
        float4 v = *(const float4*)(s + idx);
        ushort4 o;
        o.x = f2b(v.x); o.y = f2b(v.y); o.z = f2b(v.z); o.w = f2b(v.w);
        *(ushort4*)(d + idx) = o;
    }
}

// ---------------------------------------------------------------------------
// Fused weight transpose+convert: Wq|Wk|Wv (fp32, [2048][C]) -> bf16 [C][2048]
// ---------------------------------------------------------------------------
__global__ __launch_bounds__(256) void transp_conv_qkv(const float* __restrict__ Wq,
                                                       const float* __restrict__ Wk,
                                                       const float* __restrict__ Wv,
                                                       unsigned short* __restrict__ dst)
{
    __shared__ float t[32][33];
    const int tx = threadIdx.x, ty = threadIdx.y;   // (32,8)
    int bx = blockIdx.x;
    const float* src; int C, cb, dco;
    if (bx < 32)      { src = Wq; C = 1024; cb = bx;      dco = 0; }
    else if (bx < 40) { src = Wk; C = 256;  cb = bx - 32; dco = 1024; }
    else              { src = Wv; C = 256;  cb = bx - 40; dco = 1280; }
    const int c = cb * 32 + tx;
    const int r0 = blockIdx.y * 32;
#pragma unroll
    for (int i = 0; i < 4; ++i)
        t[ty + i * 8][tx] = src[(size_t)(r0 + ty + i * 8) * C + c];
    __syncthreads();
    const int cc = cb * 32 + ty;
#pragma unroll
    for (int i = 0; i < 4; ++i)
        dst[(size_t)(dco + cc + i * 8) * 2048 + r0 + tx] = f2b(t[tx][ty + i * 8]);
}

__global__ __launch_bounds__(256) void transp_conv(const float* __restrict__ src, int R, int C,
                                                   unsigned short* __restrict__ dst, int pitch)
{
    __shared__ float t[32][33];
    const int tx = threadIdx.x, ty = threadIdx.y;
    const int c = blockIdx.x * 32 + tx;
    const int r0 = blockIdx.y * 32;
#pragma unroll
    for (int i = 0; i < 4; ++i)
        t[ty + i * 8][tx] = src[(size_t)(r0 + ty + i * 8) * C + c];
    __syncthreads();
    const int cc = blockIdx.x * 32 + ty;
#pragma unroll
    for (int i = 0; i < 4; ++i)
        dst[(size_t)(cc + i * 8) * pitch + r0 + tx] = f2b(t[tx][ty + i * 8]);
}

// ---------------------------------------------------------------------------
// bf16 MFMA GEMM, B^T input: C[M][N] = A[M][K] @ Bt[N][K]^T
// 128x128 tile, BK=64, 256 threads (4 waves 2x2), DOUBLE-BUFFERED
// global_load_lds staging: tile k+1's DMA issued before computing tile k,
// ONE barrier per iteration (its vmcnt(0) drain waits on the overlapped DMA).
// LDS 64 KB/block. MODE 0: fp32 store; MODE 1: fused QKV epilogue.
// ---------------------------------------------------------------------------
template <int MODE>
__global__ __launch_bounds__(256, 2) void gemm_bt_mfma(
    const unsigned short* __restrict__ A,
    const unsigned short* __restrict__ Bt,
    int M, int N, int K,
    float* __restrict__ Cf,
    unsigned short* __restrict__ qh,
    unsigned short* __restrict__ kh,
    unsigned short* __restrict__ vtt)
{
    __shared__ __align__(16) unsigned short As[2][128 * 64];   // 16 KB each
    __shared__ __align__(16) unsigned short Bs[2][128 * 64];

    const int tid = threadIdx.x;
    const int w = tid >> 6, lane = tid & 63, l15 = lane & 15, quad = lane >> 4;
    const int wm = w & 1, wn = w >> 1;
    const int m0 = blockIdx.y * 128, n0 = blockIdx.x * 128;

    f32x4 acc[4][4];
    const f32x4 zero4 = {0.f, 0.f, 0.f, 0.f};
#pragma unroll
    for (int i = 0; i < 4; ++i)
#pragma unroll
        for (int j = 0; j < 4; ++j) acc[i][j] = zero4;

    // staging: wave w stages rows w*32..+31; per gload16: 64 lanes cover
    // 8 rows x 64 cols (lane -> row lane>>3, col (lane&7)*8); 4 issues/mat.
    const unsigned short* AgL = A  + (size_t)(m0 + w * 32 + (lane >> 3)) * K + (lane & 7) * 8;
    const unsigned short* BgL = Bt + (size_t)(n0 + w * 32 + (lane >> 3)) * K + (lane & 7) * 8;

    // prologue: stage tile 0 into buffer 0
#pragma unroll
    for (int t = 0; t < 4; ++t) {
        gload16(AgL + (size_t)(t * 8) * K, &As[0][(w * 32 + t * 8) * 64]);
        gload16(BgL + (size_t)(t * 8) * K, &Bs[0][(w * 32 + t * 8) * 64]);
    }
    __syncthreads();   // vmcnt(0) drain: tile 0 visible

    int cb = 0;
    for (int k0 = 0; k0 < K; k0 += 64) {
        // async prefetch tile k+1 into the other buffer (no wait here)
        if (k0 + 64 < K) {
            const int nb = cb ^ 1;
#pragma unroll
            for (int t = 0; t < 4; ++t) {
                gload16(AgL + (size_t)(t * 8) * K + (k0 + 64), &As[nb][(w * 32 + t * 8) * 64]);
                gload16(BgL + (size_t)(t * 8) * K + (k0 + 64), &Bs[nb][(w * 32 + t * 8) * 64]);
            }
        }

        // compute tile k from buffer cb
        bf16x8 af[4][2], bf[4][2];
#pragma unroll
        for (int t = 0; t < 4; ++t)
#pragma unroll
            for (int kk = 0; kk < 2; ++kk) {
                af[t][kk] = *(const bf16x8*)&As[cb][(wm * 64 + t * 16 + l15) * 64 + kk * 32 + quad * 8];
                bf[t][kk] = *(const bf16x8*)&Bs[cb][(wn * 64 + t * 16 + l15) * 64 + kk * 32 + quad * 8];
            }
#pragma unroll
        for (int kk = 0; kk < 2; ++kk)
#pragma unroll
            for (int mt = 0; mt < 4; ++mt)
#pragma unroll
                for (int nt = 0; nt < 4; ++nt)
                    acc[mt][nt] = MFMA_BF16(af[mt][kk], bf[nt][kk], acc[mt][nt]);

        // barrier: drains vmcnt(0) (prefetch landed) + all waves done reading cb
        __syncthreads();
        cb ^= 1;
    }

    // epilogue: C/D layout col = l15 (+16*nt), row = quad*4 + r (+16*mt)
    if (MODE == 0) {
#pragma unroll
        for (int mt = 0; mt < 4; ++mt)
#pragma unroll
            for (int nt = 0; nt < 4; ++nt) {
                const int gn = n0 + wn * 64 + nt * 16 + l15;
#pragma unroll
                for (int r = 0; r < 4; ++r) {
                    const int gm = m0 + wm * 64 + mt * 16 + quad * 4 + r;
                    Cf[(size_t)gm * N + gn] = acc[mt][nt][r];
                }
            }
    } else {
        if (n0 < 1024) {            // Q: tanh -> qh[m][n], pitch 1024
#pragma unroll
            for (int mt = 0; mt < 4; ++mt)
#pragma unroll
                for (int nt = 0; nt < 4; ++nt) {
                    const int gn = n0 + wn * 64 + nt * 16 + l15;
#pragma unroll
                    for (int r = 0; r < 4; ++r) {
                        const int gm = m0 + wm * 64 + mt * 16 + quad * 4 + r;
                        qh[(size_t)gm * 1024 + gn] = f2b(tanhf(acc[mt][nt][r]));
                    }
                }
        } else if (n0 < 1280) {     // K: tanh -> kh[m][n-1024], pitch 256
#pragma unroll
            for (int mt = 0; mt < 4; ++mt)
#pragma unroll
                for (int nt = 0; nt < 4; ++nt) {
                    const int gn = n0 + wn * 64 + nt * 16 + l15 - 1024;
#pragma unroll
                    for (int r = 0; r < 4; ++r) {
                        const int gm = m0 + wm * 64 + mt * 16 + quad * 4 + r;
                        kh[(size_t)gm * 256 + gn] = f2b(tanhf(acc[mt][nt][r]));
                    }
                }
        } else {                    // V: sigmoid -> vtt[(b*4+g)*64+v][s]
#pragma unroll
            for (int mt = 0; mt < 4; ++mt)
#pragma unroll
                for (int nt = 0; nt < 4; ++nt) {
                    const int gn = n0 + wn * 64 + nt * 16 + l15 - 1280;
                    const int g = gn >> 6, vv = gn & 63;
                    const int s0 = m0 + wm * 64 + mt * 16 + quad * 4;
                    const int b = s0 >> 11, sl = s0 & 2047;
                    ushort4 pk;
                    unsigned short* pp = (unsigned short*)&pk;
#pragma unroll
                    for (int r = 0; r < 4; ++r) {
                        float sv = 1.0f / (1.0f + __expf(-acc[mt][nt][r]));
                        pp[r] = f2b(sv);
                    }
                    *(ushort4*)&vtt[((size_t)(b * 4 + g) * 64 + vv) * 2048 + sl] = pk;
                }
        }
    }
}

// ---------------------------------------------------------------------------
// MFMA flash attention, fixed-max softmax, pipelined double-buffered staging.
// (unchanged from R4)
// ---------------------------------------------------------------------------
__global__ __launch_bounds__(256) void rosa_attn_mfma(
    const unsigned short* __restrict__ qh,
    const unsigned short* __restrict__ kh,
    const unsigned short* __restrict__ vtt,
    const int* __restrict__ amask,
    const float* __restrict__ emb0,
    const float* __restrict__ emb1,
    unsigned short* __restrict__ ob)
{
    __shared__ __align__(16) unsigned short Ks[2][64][72];
    __shared__ __align__(16) unsigned short Vs[2][64][72];
    __shared__ __align__(16) unsigned short Ps[4][16][72];
    __shared__ float Mskf[2][64];

    const int pairI = blockIdx.x;
    const int h = blockIdx.y, b = blockIdx.z, g = h >> 2;
    const int tid = threadIdx.x;
    const int w = tid >> 6, lane = tid & 63, l15 = lane & 15, quad = lane >> 4;

    const int srow0 = tid >> 3,         soff0 = (tid & 7) * 8;
    const int srow1 = (tid + 256) >> 3, soff1 = ((tid + 256) & 7) * 8;

    const unsigned short* kbase = kh + (size_t)b * 2048 * 256 + g * 64;
    const unsigned short* vbase = vtt + ((size_t)(b * 4 + g) * 64) * 2048;

    const f32x4 zero4 = {0.f, 0.f, 0.f, 0.f};
    const float cexp = 0.0225421100f;             // log2(e)/64

    for (int half = 0; half < 2; ++half) {
        const int qt = (half == 0) ? pairI : 31 - pairI;
        const int q0 = qt * 64;
        const int nkt = qt + 1;
        const int qg = q0 + w * 16 + l15;

        const unsigned short* qrow = qh + ((size_t)(b * 2048 + q0 + w * 16 + l15) * 16 + h) * 64;
        const bf16x8 qf0 = *(const bf16x8*)(qrow + quad * 8);
        const bf16x8 qf1 = *(const bf16x8*)(qrow + 32 + quad * 8);

        f32x4 oacc[4];
#pragma unroll
        for (int t = 0; t < 4; ++t) oacc[t] = zero4;
        float psum = 0.0f;

        __syncthreads();
        {
            uint4 k0r = *(const uint4*)(kbase + (size_t)srow0 * 256 + soff0);
            uint4 k1r = *(const uint4*)(kbase + (size_t)srow1 * 256 + soff1);
            uint4 v0r = *(const uint4*)(vbase + (size_t)srow0 * 2048 + soff0);
            uint4 v1r = *(const uint4*)(vbase + (size_t)srow1 * 2048 + soff1);
            int mr = (tid < 64) ? amask[b * 2048 + tid] : 0;
            *(uint4*)&Ks[0][srow0][soff0] = k0r;
            *(uint4*)&Ks[0][srow1][soff1] = k1r;
            *(uint4*)&Vs[0][srow0][soff0] = v0r;
            *(uint4*)&Vs[0][srow1][soff1] = v1r;
            if (tid < 64) Mskf[0][tid] = mr ? 1.0f : 0.0f;
        }
        __syncthreads();

        int cb = 0;
        for (int kt = 0; kt < nkt; ++kt) {
            const bool haveNext = (kt + 1 < nkt);
            uint4 k0r, k1r, v0r, v1r;
            int mr = 0;
            if (haveNext) {
                const int kn = (kt + 1) * 64;
                k0r = *(const uint4*)(kbase + (size_t)(kn + srow0) * 256 + soff0);
                k1r = *(const uint4*)(kbase + (size_t)(kn + srow1) * 256 + soff1);
                v0r = *(const uint4*)(vbase + (size_t)srow0 * 2048 + kn + soff0);
                v1r = *(const uint4*)(vbase + (size_t)srow1 * 2048 + kn + soff1);
                if (tid < 64) mr = amask[b * 2048 + kn + tid];
            }

            const int k0 = kt * 64;
            const bool diag = (kt == qt);
            const int ntlim = diag ? (w + 1) : 4;

#pragma unroll
            for (int nt = 0; nt < 4; ++nt) {
                ushort4 pk;
                if (nt < ntlim) {
                    bf16x8 kf0 = *(const bf16x8*)&Ks[cb][nt * 16 + l15][quad * 8];
                    bf16x8 kf1 = *(const bf16x8*)&Ks[cb][nt * 16 + l15][32 + quad * 8];
                    f32x4 sc = MFMA_BF16(kf0, qf0, zero4);
                    sc = MFMA_BF16(kf1, qf1, sc);
                    float4 mv = *(const float4*)&Mskf[cb][nt * 16 + quad * 4];
                    const float* mvp = (const float*)&mv;
                    unsigned short* pp = (unsigned short*)&pk;
#pragma unroll
                    for (int r = 0; r < 4; ++r) {
                        float p = __builtin_exp2f(sc[r] * cexp) * mvp[r];
                        if (diag) {
                            const int jg = k0 + nt * 16 + quad * 4 + r;
                            p = (jg <= qg) ? p : 0.0f;
                        }
                        psum += p;
                        pp[r] = f2b(p);
                    }
                } else {
                    pk.x = 0; pk.y = 0; pk.z = 0; pk.w = 0;
                }
                *(ushort4*)&Ps[w][l15][nt * 16 + quad * 4] = pk;
            }

            const bf16x8 pf0 = *(const bf16x8*)&Ps[w][l15][quad * 8];
            const bf16x8 pf1 = *(const bf16x8*)&Ps[w][l15][32 + quad * 8];
#pragma unroll
            for (int nt = 0; nt < 4; ++nt) {
                bf16x8 vf0 = *(const bf16x8*)&Vs[cb][nt * 16 + l15][quad * 8];
                bf16x8 vf1 = *(const bf16x8*)&Vs[cb][nt * 16 + l15][32 + quad * 8];
                oacc[nt] = MFMA_BF16(pf0, vf0, oacc[nt]);
                oacc[nt] = MFMA_BF16(pf1, vf1, oacc[nt]);
            }

            if (haveNext) {
                const int nb = cb ^ 1;
                *(uint4*)&Ks[nb][srow0][soff0] = k0r;
                *(uint4*)&Ks[nb][srow1][soff1] = k1r;
                *(uint4*)&Vs[nb][srow0][soff0] = v0r;
                *(uint4*)&Vs[nb][srow1][soff1] = v1r;
                if (tid < 64) Mskf[nb][tid] = mr ? 1.0f : 0.0f;
                __syncthreads();
                cb = nb;
            }
        }

        float l = psum;
        l += __shfl_xor(l, 16);
        l += __shfl_xor(l, 32);
        float lq[4];
#pragma unroll
        for (int r = 0; r < 4; ++r) lq[r] = __shfl(l, quad * 4 + r);

#pragma unroll
        for (int nt = 0; nt < 4; ++nt) {
            const float e0 = emb0[h * 64 + nt * 16 + l15];
            const float e1 = emb1[h * 64 + nt * 16 + l15];
#pragma unroll
            for (int r = 0; r < 4; ++r) {
                const float ctx = oacc[nt][r] / lq[r];
                const float val = e0 + ctx * (e1 - e0);
                const size_t s_idx = (size_t)(b * 2048 + q0 + w * 16 + quad * 4 + r);
                ob[(s_idx * 16 + h) * 64 + nt * 16 + l15] = f2b(val);
            }
        }
    }
}

// ---------------------------------------------------------------------------
extern "C" void kernel_launch(void* const* d_in, const int* in_sizes, int n_in,
                              void* d_out, int out_size, void* d_ws, size_t ws_size,
                              hipStream_t stream)
{
    const float* x    = (const float*)d_in[0];
    const int*   amask= (const int*)d_in[1];
    const float* Wq   = (const float*)d_in[2];
    const float* Wk   = (const float*)d_in[3];
    const float* Wv   = (const float*)d_in[4];
    const float* Wo   = (const float*)d_in[5];
    const float* emb0 = (const float*)d_in[6];
    const float* emb1 = (const float*)d_in[7];
    float* out = (float*)d_out;

    char* base = (char*)d_ws;
    unsigned short* xh    = (unsigned short*)(base);                      // 16 MB
    unsigned short* ob    = xh;                                           // aliases xh
    unsigned short* Wqkvt = (unsigned short*)(base + (16u << 20));        // 6 MB
    unsigned short* Wot   = (unsigned short*)(base + (22u << 20));        // 4 MB
    unsigned short* qh    = (unsigned short*)(base + (26u << 20));        // 8 MB
    unsigned short* kh    = (unsigned short*)(base + (34u << 20));        // 2 MB
    unsigned short* vtt   = (unsigned short*)(base + (36u << 20));        // 2 MB

    conv_bf16<<<2048, 256, 0, stream>>>(x, xh, 4096 * 2048);
    transp_conv_qkv<<<dim3(48, 64), dim3(32, 8), 0, stream>>>(Wq, Wk, Wv, Wqkvt);
    transp_conv<<<dim3(64, 32), dim3(32, 8), 0, stream>>>(Wo, 1024, 2048, Wot, 1024);

    gemm_bt_mfma<1><<<dim3(12, 32), 256, 0, stream>>>(xh, Wqkvt, 4096, 1536, 2048,
                                                      nullptr, qh, kh, vtt);
    rosa_attn_mfma<<<dim3(16, 16, 2), 256, 0, stream>>>(qh, kh, vtt, amask, emb0, emb1, ob);
    gemm_bt_mfma<0><<<dim3(16, 32), 256, 0, stream>>>(ob, Wot, 4096, 2048, 1024,
                                                      out, nullptr, nullptr, nullptr);
}

// Round 7
// 238.057 us; speedup vs baseline: 1.8774x; 1.0364x over previous
//
#include <hip/hip_runtime.h>
#include <math.h>

typedef short bf16x8 __attribute__((ext_vector_type(8)));
typedef float f32x4 __attribute__((ext_vector_type(4)));

#define MFMA_BF16(A,B,C) __builtin_amdgcn_mfma_f32_16x16x32_bf16(A,B,C,0,0,0)

__device__ __forceinline__ unsigned short f2b(float x) {
    union { float f; unsigned int u; } v; v.f = x;
    unsigned int r = v.u + 0x7FFFu + ((v.u >> 16) & 1u);
    return (unsigned short)(r >> 16);
}

// async global->LDS DMA, 16B per lane; LDS dest = wave-uniform base + lane*16
__device__ __forceinline__ void gload16(const unsigned short* g, unsigned short* l) {
    __builtin_amdgcn_global_load_lds(
        (const __attribute__((address_space(1))) unsigned int*)(g),
        (__attribute__((address_space(3))) unsigned int*)(l),
        16, 0, 0);
}

// ---------------------------------------------------------------------------
// fp32 -> bf16 convert (flat)
// ---------------------------------------------------------------------------
__global__ __launch_bounds__(256) void conv_bf16(const float* __restrict__ s,
                                                 unsigned short* __restrict__ d, int n)
{
    int i = blockIdx.x * blockDim.x + threadIdx.x;
    int stride = gridDim.x * blockDim.x;
    for (int idx = i * 4; idx < n; idx += stride * 4) {
        float4 v = *(const float4*)(s + idx);
        ushort4 o;
        o.x = f2b(v.x); o.y = f2b(v.y); o.z = f2b(v.z); o.w = f2b(v.w);
        *(ushort4*)(d + idx) = o;
    }
}

// ---------------------------------------------------------------------------
// Fused weight transpose+convert: Wq|Wk|Wv (fp32, [2048][C]) -> bf16 [C][2048]
// ---------------------------------------------------------------------------
__global__ __launch_bounds__(256) void transp_conv_qkv(const float* __restrict__ Wq,
                                                       const float* __restrict__ Wk,
                                                       const float* __restrict__ Wv,
                                                       unsigned short* __restrict__ dst)
{
    __shared__ float t[32][33];
    const int tx = threadIdx.x, ty = threadIdx.y;   // (32,8)
    int bx = blockIdx.x;
    const float* src; int C, cb, dco;
    if (bx < 32)      { src = Wq; C = 1024; cb = bx;      dco = 0; }
    else if (bx < 40) { src = Wk; C = 256;  cb = bx - 32; dco = 1024; }
    else              { src = Wv; C = 256;  cb = bx - 40; dco = 1280; }
    const int c = cb * 32 + tx;
    const int r0 = blockIdx.y * 32;
#pragma unroll
    for (int i = 0; i < 4; ++i)
        t[ty + i * 8][tx] = src[(size_t)(r0 + ty + i * 8) * C + c];
    __syncthreads();
    const int cc = cb * 32 + ty;
#pragma unroll
    for (int i = 0; i < 4; ++i)
        dst[(size_t)(dco + cc + i * 8) * 2048 + r0 + tx] = f2b(t[tx][ty + i * 8]);
}

__global__ __launch_bounds__(256) void transp_conv(const float* __restrict__ src, int R, int C,
                                                   unsigned short* __restrict__ dst, int pitch)
{
    __shared__ float t[32][33];
    const int tx = threadIdx.x, ty = threadIdx.y;
    const int c = blockIdx.x * 32 + tx;
    const int r0 = blockIdx.y * 32;
#pragma unroll
    for (int i = 0; i < 4; ++i)
        t[ty + i * 8][tx] = src[(size_t)(r0 + ty + i * 8) * C + c];
    __syncthreads();
    const int cc = blockIdx.x * 32 + ty;
#pragma unroll
    for (int i = 0; i < 4; ++i)
        dst[(size_t)(cc + i * 8) * pitch + r0 + tx] = f2b(t[tx][ty + i * 8]);
}

// ---------------------------------------------------------------------------
// bf16 MFMA GEMM, B^T input: C[M][N] = A[M][K] @ Bt[N][K]^T
// BM=128, BN=64, BK=64; 256 threads (4 waves, 2x2: wm in {0,1} x 64 rows,
// wn in {0,1} x 32 cols); double-buffered global_load_lds staging.
// LDS stored as TWO pitch-32 sub-tiles per buffer ([kk][row][32]) to keep
// m97's bank geometry for ds_read_b128 (pitch-64 was a 16-way conflict).
// Grid doubles vs 128x128 -> 3 blocks/CU of TLP to cover the barrier drain.
// MODE 0: fp32 store; MODE 1: fused QKV epilogue.
// ---------------------------------------------------------------------------
template <int MODE>
__global__ __launch_bounds__(256, 3) void gemm_bt_mfma(
    const unsigned short* __restrict__ A,
    const unsigned short* __restrict__ Bt,
    int M, int N, int K,
    float* __restrict__ Cf,
    unsigned short* __restrict__ qh,
    unsigned short* __restrict__ kh,
    unsigned short* __restrict__ vtt)
{
    __shared__ __align__(16) unsigned short As[2][2 * 128 * 32];   // [buf][kk*4096+row*32+c]
    __shared__ __align__(16) unsigned short Bs[2][2 * 64 * 32];    // [buf][kk*2048+row*32+c]

    const int tid = threadIdx.x;
    const int w = tid >> 6, lane = tid & 63, l15 = lane & 15, quad = lane >> 4;
    const int wm = w & 1, wn = w >> 1;
    const int m0 = blockIdx.y * 128, n0 = blockIdx.x * 64;

    f32x4 acc[4][2];
    const f32x4 zero4 = {0.f, 0.f, 0.f, 0.f};
#pragma unroll
    for (int i = 0; i < 4; ++i)
#pragma unroll
        for (int j = 0; j < 2; ++j) acc[i][j] = zero4;

    // staging lane geometry: 1 issue = 16 rows x 32 cols (lane -> row lane>>2,
    // col (lane&3)*8); LDS lands at base + lane*16B = lane*8 elems.
    const int lrow = lane >> 2, lcol = (lane & 3) * 8;
    // A: wave w stages rows w*32..+31, 2 sub-tiles x 2 halves = 4 issues.
    const unsigned short* AgL = A  + (size_t)(m0 + w * 32 + lrow) * K + lcol;
    // B: wave w stages rows w*16..+15, 2 sub-tiles = 2 issues.
    const unsigned short* BgL = Bt + (size_t)(n0 + w * 16 + lrow) * K + lcol;

    // prologue: stage tile 0 into buffer 0
#pragma unroll
    for (int t = 0; t < 4; ++t) {
        const int sub = t >> 1, half = t & 1;
        gload16(AgL + (size_t)(half * 16) * K + sub * 32,
                &As[0][sub * 4096 + (w * 32 + half * 16) * 32]);
    }
#pragma unroll
    for (int kk = 0; kk < 2; ++kk)
        gload16(BgL + kk * 32, &Bs[0][kk * 2048 + (w * 16) * 32]);
    __syncthreads();

    int cb = 0;
    for (int k0 = 0; k0 < K; k0 += 64) {
        // async prefetch tile k+1 into the other buffer
        if (k0 + 64 < K) {
            const int nb = cb ^ 1;
#pragma unroll
            for (int t = 0; t < 4; ++t) {
                const int sub = t >> 1, half = t & 1;
                gload16(AgL + (size_t)(half * 16) * K + (k0 + 64) + sub * 32,
                        &As[nb][sub * 4096 + (w * 32 + half * 16) * 32]);
            }
#pragma unroll
            for (int kk = 0; kk < 2; ++kk)
                gload16(BgL + (k0 + 64) + kk * 32, &Bs[nb][kk * 2048 + (w * 16) * 32]);
        }

        // compute tile k from buffer cb
        bf16x8 af[4][2], bf[2][2];
#pragma unroll
        for (int kk = 0; kk < 2; ++kk) {
#pragma unroll
            for (int mt = 0; mt < 4; ++mt)
                af[mt][kk] = *(const bf16x8*)&As[cb][kk * 4096 + (wm * 64 + mt * 16 + l15) * 32 + quad * 8];
#pragma unroll
            for (int nt = 0; nt < 2; ++nt)
                bf[nt][kk] = *(const bf16x8*)&Bs[cb][kk * 2048 + (wn * 32 + nt * 16 + l15) * 32 + quad * 8];
        }
#pragma unroll
        for (int kk = 0; kk < 2; ++kk)
#pragma unroll
            for (int mt = 0; mt < 4; ++mt)
#pragma unroll
                for (int nt = 0; nt < 2; ++nt)
                    acc[mt][nt] = MFMA_BF16(af[mt][kk], bf[nt][kk], acc[mt][nt]);

        __syncthreads();   // drain: prefetch landed + all waves done reading cb
        cb ^= 1;
    }

    // epilogue: C/D layout col = l15 (+16*nt), row = quad*4 + r (+16*mt)
    if (MODE == 0) {
#pragma unroll
        for (int mt = 0; mt < 4; ++mt)
#pragma unroll
            for (int nt = 0; nt < 2; ++nt) {
                const int gn = n0 + wn * 32 + nt * 16 + l15;
#pragma unroll
                for (int r = 0; r < 4; ++r) {
                    const int gm = m0 + wm * 64 + mt * 16 + quad * 4 + r;
                    Cf[(size_t)gm * N + gn] = acc[mt][nt][r];
                }
            }
    } else {
        if (n0 < 1024) {            // Q: tanh -> qh[m][n], pitch 1024
#pragma unroll
            for (int mt = 0; mt < 4; ++mt)
#pragma unroll
                for (int nt = 0; nt < 2; ++nt) {
                    const int gn = n0 + wn * 32 + nt * 16 + l15;
#pragma unroll
                    for (int r = 0; r < 4; ++r) {
                        const int gm = m0 + wm * 64 + mt * 16 + quad * 4 + r;
                        qh[(size_t)gm * 1024 + gn] = f2b(tanhf(acc[mt][nt][r]));
                    }
                }
        } else if (n0 < 1280) {     // K: tanh -> kh[m][n-1024], pitch 256
#pragma unroll
            for (int mt = 0; mt < 4; ++mt)
#pragma unroll
                for (int nt = 0; nt < 2; ++nt) {
                    const int gn = n0 + wn * 32 + nt * 16 + l15 - 1024;
#pragma unroll
                    for (int r = 0; r < 4; ++r) {
                        const int gm = m0 + wm * 64 + mt * 16 + quad * 4 + r;
                        kh[(size_t)gm * 256 + gn] = f2b(tanhf(acc[mt][nt][r]));
                    }
                }
        } else {                    // V: sigmoid -> vtt[(b*4+g)*64+v][s]
#pragma unroll
            for (int mt = 0; mt < 4; ++mt)
#pragma unroll
                for (int nt = 0; nt < 2; ++nt) {
                    const int gn = n0 + wn * 32 + nt * 16 + l15 - 1280;
                    const int g = gn >> 6, vv = gn & 63;
                    const int s0 = m0 + wm * 64 + mt * 16 + quad * 4;
                    const int b = s0 >> 11, sl = s0 & 2047;
                    ushort4 pk;
                    unsigned short* pp = (unsigned short*)&pk;
#pragma unroll
                    for (int r = 0; r < 4; ++r) {
                        float sv = 1.0f / (1.0f + __expf(-acc[mt][nt][r]));
                        pp[r] = f2b(sv);
                    }
                    *(ushort4*)&vtt[((size_t)(b * 4 + g) * 64 + vv) * 2048 + sl] = pk;
                }
        }
    }
}

// ---------------------------------------------------------------------------
// MFMA flash attention, fixed-max softmax, pipelined double-buffered staging.
// (unchanged from R4)
// ---------------------------------------------------------------------------
__global__ __launch_bounds__(256) void rosa_attn_mfma(
    const unsigned short* __restrict__ qh,
    const unsigned short* __restrict__ kh,
    const unsigned short* __restrict__ vtt,
    const int* __restrict__ amask,
    const float* __restrict__ emb0,
    const float* __restrict__ emb1,
    unsigned short* __restrict__ ob)
{
    __shared__ __align__(16) unsigned short Ks[2][64][72];
    __shared__ __align__(16) unsigned short Vs[2][64][72];
    __shared__ __align__(16) unsigned short Ps[4][16][72];
    __shared__ float Mskf[2][64];

    const int pairI = blockIdx.x;
    const int h = blockIdx.y, b = blockIdx.z, g = h >> 2;
    const int tid = threadIdx.x;
    const int w = tid >> 6, lane = tid & 63, l15 = lane & 15, quad = lane >> 4;

    const int srow0 = tid >> 3,         soff0 = (tid & 7) * 8;
    const int srow1 = (tid + 256) >> 3, soff1 = ((tid + 256) & 7) * 8;

    const unsigned short* kbase = kh + (size_t)b * 2048 * 256 + g * 64;
    const unsigned short* vbase = vtt + ((size_t)(b * 4 + g) * 64) * 2048;

    const f32x4 zero4 = {0.f, 0.f, 0.f, 0.f};
    const float cexp = 0.0225421100f;             // log2(e)/64

    for (int half = 0; half < 2; ++half) {
        const int qt = (half == 0) ? pairI : 31 - pairI;
        const int q0 = qt * 64;
        const int nkt = qt + 1;
        const int qg = q0 + w * 16 + l15;

        const unsigned short* qrow = qh + ((size_t)(b * 2048 + q0 + w * 16 + l15) * 16 + h) * 64;
        const bf16x8 qf0 = *(const bf16x8*)(qrow + quad * 8);
        const bf16x8 qf1 = *(const bf16x8*)(qrow + 32 + quad * 8);

        f32x4 oacc[4];
#pragma unroll
        for (int t = 0; t < 4; ++t) oacc[t] = zero4;
        float psum = 0.0f;

        __syncthreads();
        {
            uint4 k0r = *(const uint4*)(kbase + (size_t)srow0 * 256 + soff0);
            uint4 k1r = *(const uint4*)(kbase + (size_t)srow1 * 256 + soff1);
            uint4 v0r = *(const uint4*)(vbase + (size_t)srow0 * 2048 + soff0);
            uint4 v1r = *(const uint4*)(vbase + (size_t)srow1 * 2048 + soff1);
            int mr = (tid < 64) ? amask[b * 2048 + tid] : 0;
            *(uint4*)&Ks[0][srow0][soff0] = k0r;
            *(uint4*)&Ks[0][srow1][soff1] = k1r;
            *(uint4*)&Vs[0][srow0][soff0] = v0r;
            *(uint4*)&Vs[0][srow1][soff1] = v1r;
            if (tid < 64) Mskf[0][tid] = mr ? 1.0f : 0.0f;
        }
        __syncthreads();

        int cb = 0;
        for (int kt = 0; kt < nkt; ++kt) {
            const bool haveNext = (kt + 1 < nkt);
            uint4 k0r, k1r, v0r, v1r;
            int mr = 0;
            if (haveNext) {
                const int kn = (kt + 1) * 64;
                k0r = *(const uint4*)(kbase + (size_t)(kn + srow0) * 256 + soff0);
                k1r = *(const uint4*)(kbase + (size_t)(kn + srow1) * 256 + soff1);
                v0r = *(const uint4*)(vbase + (size_t)srow0 * 2048 + kn + soff0);
                v1r = *(const uint4*)(vbase + (size_t)srow1 * 2048 + kn + soff1);
                if (tid < 64) mr = amask[b * 2048 + kn + tid];
            }

            const int k0 = kt * 64;
            const bool diag = (kt == qt);
            const int ntlim = diag ? (w + 1) : 4;

#pragma unroll
            for (int nt = 0; nt < 4; ++nt) {
                ushort4 pk;
                if (nt < ntlim) {
                    bf16x8 kf0 = *(const bf16x8*)&Ks[cb][nt * 16 + l15][quad * 8];
                    bf16x8 kf1 = *(const bf16x8*)&Ks[cb][nt * 16 + l15][32 + quad * 8];
                    f32x4 sc = MFMA_BF16(kf0, qf0, zero4);
                    sc = MFMA_BF16(kf1, qf1, sc);
                    float4 mv = *(const float4*)&Mskf[cb][nt * 16 + quad * 4];
                    const float* mvp = (const float*)&mv;
                    unsigned short* pp = (unsigned short*)&pk;
#pragma unroll
                    for (int r = 0; r < 4; ++r) {
                        float p = __builtin_exp2f(sc[r] * cexp) * mvp[r];
                        if (diag) {
                            const int jg = k0 + nt * 16 + quad * 4 + r;
                            p = (jg <= qg) ? p : 0.0f;
                        }
                        psum += p;
                        pp[r] = f2b(p);
                    }
                } else {
                    pk.x = 0; pk.y = 0; pk.z = 0; pk.w = 0;
                }
                *(ushort4*)&Ps[w][l15][nt * 16 + quad * 4] = pk;
            }

            const bf16x8 pf0 = *(const bf16x8*)&Ps[w][l15][quad * 8];
            const bf16x8 pf1 = *(const bf16x8*)&Ps[w][l15][32 + quad * 8];
#pragma unroll
            for (int nt = 0; nt < 4; ++nt) {
                bf16x8 vf0 = *(const bf16x8*)&Vs[cb][nt * 16 + l15][quad * 8];
                bf16x8 vf1 = *(const bf16x8*)&Vs[cb][nt * 16 + l15][32 + quad * 8];
                oacc[nt] = MFMA_BF16(pf0, vf0, oacc[nt]);
                oacc[nt] = MFMA_BF16(pf1, vf1, oacc[nt]);
            }

            if (haveNext) {
                const int nb = cb ^ 1;
                *(uint4*)&Ks[nb][srow0][soff0] = k0r;
                *(uint4*)&Ks[nb][srow1][soff1] = k1r;
                *(uint4*)&Vs[nb][srow0][soff0] = v0r;
                *(uint4*)&Vs[nb][srow1][soff1] = v1r;
                if (tid < 64) Mskf[nb][tid] = mr ? 1.0f : 0.0f;
                __syncthreads();
                cb = nb;
            }
        }

        float l = psum;
        l += __shfl_xor(l, 16);
        l += __shfl_xor(l, 32);
        float lq[4];
#pragma unroll
        for (int r = 0; r < 4; ++r) lq[r] = __shfl(l, quad * 4 + r);

#pragma unroll
        for (int nt = 0; nt < 4; ++nt) {
            const float e0 = emb0[h * 64 + nt * 16 + l15];
            const float e1 = emb1[h * 64 + nt * 16 + l15];
#pragma unroll
            for (int r = 0; r < 4; ++r) {
                const float ctx = oacc[nt][r] / lq[r];
                const float val = e0 + ctx * (e1 - e0);
                const size_t s_idx = (size_t)(b * 2048 + q0 + w * 16 + quad * 4 + r);
                ob[(s_idx * 16 + h) * 64 + nt * 16 + l15] = f2b(val);
            }
        }
    }
}

// ---------------------------------------------------------------------------
extern "C" void kernel_launch(void* const* d_in, const int* in_sizes, int n_in,
                              void* d_out, int out_size, void* d_ws, size_t ws_size,
                              hipStream_t stream)
{
    const float* x    = (const float*)d_in[0];
    const int*   amask= (const int*)d_in[1];
    const float* Wq   = (const float*)d_in[2];
    const float* Wk   = (const float*)d_in[3];
    const float* Wv   = (const float*)d_in[4];
    const float* Wo   = (const float*)d_in[5];
    const float* emb0 = (const float*)d_in[6];
    const float* emb1 = (const float*)d_in[7];
    float* out = (float*)d_out;

    char* base = (char*)d_ws;
    unsigned short* xh    = (unsigned short*)(base);                      // 16 MB
    unsigned short* ob    = xh;                                           // aliases xh
    unsigned short* Wqkvt = (unsigned short*)(base + (16u << 20));        // 6 MB
    unsigned short* Wot   = (unsigned short*)(base + (22u << 20));        // 4 MB
    unsigned short* qh    = (unsigned short*)(base + (26u << 20));        // 8 MB
    unsigned short* kh    = (unsigned short*)(base + (34u << 20));        // 2 MB
    unsigned short* vtt   = (unsigned short*)(base + (36u << 20));        // 2 MB

    conv_bf16<<<2048, 256, 0, stream>>>(x, xh, 4096 * 2048);
    transp_conv_qkv<<<dim3(48, 64), dim3(32, 8), 0, stream>>>(Wq, Wk, Wv, Wqkvt);
    transp_conv<<<dim3(64, 32), dim3(32, 8), 0, stream>>>(Wo, 1024, 2048, Wot, 1024);

    gemm_bt_mfma<1><<<dim3(24, 32), 256, 0, stream>>>(xh, Wqkvt, 4096, 1536, 2048,
                                                      nullptr, qh, kh, vtt);
    rosa_attn_mfma<<<dim3(16, 16, 2), 256, 0, stream>>>(qh, kh, vtt, amask, emb0, emb1, ob);
    gemm_bt_mfma<0><<<dim3(32, 32), 256, 0, stream>>>(ob, Wot, 4096, 2048, 1024,
                                                      out, nullptr, nullptr, nullptr);
}